// Round 8
// baseline (185.454 us; speedup 1.0000x reference)
//
#include <hip/hip_runtime.h>
#include <math.h>

// SSIM fused single pass, v8.
// R5-R7 post-mortem: the 88-float/thread scatter state (2px) forced
// AGPR banking (~+130 VALU movs/iter) AND capped residency at 2 waves/SIMD
// (total regs/wave >170); __threadfence_block's vmcnt(0) drained the global
// prefetch every iter (~40% stall at 2 resident waves). v8:
//  * 1 px/thread, 4 quantities: acc = 11 slots x 2 v2f = 44 floats; peak live
//    ~80 regs -> fits the 128-reg budget of __launch_bounds__(256,4), no
//    banking, 4 waves/SIMD residency (16 waves/CU).
//  * LDS-only fence: asm s_waitcnt lgkmcnt(0) + "memory" clobber. Orders the
//    wave-private ds_write -> ds_read (the R3 compiler-reordering bug) without
//    draining vmcnt -> global prefetch stays in flight across iters.
//  * Everything else from the best measured config (R5): TY=34 (44 iters,
//    best halo amortization), wave-private double-buffered LDS rows, register
//    prefetch of row j+1, first-tap assign scatter, rcp division (~1e-7 err).

#define KW 11
#define RAD 5
#define IMG_W 512
#define IMG_H 512
#define TY 34                // output rows per wave tile; 44 iters = 4*11 phases
#define NJB 4
#define LROW 74              // 64 + 2*RAD staged (a,b) pairs per wave row
#define C1F 0.0001f          // 0.01^2
#define C2F 0.0009f          // 0.03^2

typedef float v2f __attribute__((ext_vector_type(2)));

__global__ __launch_bounds__(256, 4) void ssim_fused_kernel(
    const float* __restrict__ img1,
    const float* __restrict__ img2,
    float* __restrict__ out,
    float inv_n)
{
    __shared__ v2f rows[4][2][LROW];   // [wave][double-buffer][(a,b) pairs]
    __shared__ float red[4];

    const int tid  = threadIdx.x;
    const int lane = tid & 63;
    const int wvi  = tid >> 6;

    const int x0 = (blockIdx.x * 4 + wvi) * 64;   // wave's 64-col strip
    const int y0 = blockIdx.y * TY;               // wave's first output row

    const size_t pbase = (size_t)blockIdx.z * (size_t)(IMG_W * IMG_H);
    const float* __restrict__ p1 = img1 + pbase;
    const float* __restrict__ p2 = img2 + pbase;

    // Gaussian weights in double (matches float64 np reference), SGPR-pinned.
    float g[KW];
    {
        double t[KW];
        double s = 0.0;
        #pragma unroll
        for (int i = 0; i < KW; ++i) {
            const double c = (double)(i - RAD);
            t[i] = exp(-(c * c) / 4.5);   // 2*sigma^2 = 4.5
            s += t[i];
        }
        #pragma unroll
        for (int i = 0; i < KW; ++i) {
            const float gi = (float)(t[i] / s);
            g[i] = __int_as_float(__builtin_amdgcn_readfirstlane(__float_as_int(gi)));
        }
    }

    // Loop-invariant per-lane column geometry (clamped addr + mask-multiply).
    const int c0   = x0 - RAD + lane;                  // main pair col
    const int c0c  = min(max(c0, 0), IMG_W - 1);
    const float m0 = (c0 == c0c) ? 1.f : 0.f;
    const int c1   = c0 + 64;                          // halo pair (lanes 0..9)
    const int c1c  = min(max(c1, 0), IMG_W - 1);
    const float m1 = (c1 == c1c) ? 1.f : 0.f;
    const bool halo = (lane < 2 * RAD);

    // Load row (y0-RAD+j) into masked (a,b) register pairs.
    auto load_row = [&](int j, v2f& vm, v2f& vh) {
        const int ir = y0 - RAD + j;
        vm = (v2f){0.f, 0.f};
        vh = (v2f){0.f, 0.f};
        if ((unsigned)ir < (unsigned)IMG_H) {   // wave-uniform branch
            const float* r1 = p1 + ir * IMG_W;
            const float* r2 = p2 + ir * IMG_W;
            vm = (v2f){r1[c0c] * m0, r2[c0c] * m0};
            if (halo) vh = (v2f){r1[c1c] * m1, r2[c1c] * m1};
        }
    };

    // V scatter accumulators (col x0+lane): slot s holds output row m with
    // m%11==s.  (mu1,mu2) and (S=E[x^2]+E[y^2], P=E[xy]) per slot.
    v2f aMu[KW], aSP[KW];
    #pragma unroll
    for (int s = 0; s < KW; ++s) {
        aMu[s] = (v2f){0.f, 0.f};
        aSP[s] = (v2f){0.f, 0.f};
    }

    v2f curm, curh;
    load_row(0, curm, curh);

    float acc = 0.f;

    #pragma clang loop unroll(disable)
    for (int jb = 0; jb < NJB; ++jb) {
        #pragma unroll
        for (int P = 0; P < KW; ++P) {
            const int j   = jb * KW + P;        // 0..43
            const int buf = j & 1;
            v2f* __restrict__ wrow = rows[wvi][buf];

            // ---- stage row j (regs -> wave-private LDS) ----
            wrow[lane] = curm;                          // ds_write_b64
            if (halo) wrow[64 + lane] = curh;
            // LDS-only fence: orders W_j < R_j (and R_j < W_{j+2} via F_{j+1})
            // at both compiler level ("memory" clobber) and HW level
            // (lgkmcnt(0)), WITHOUT draining the global prefetch (vmcnt).
            asm volatile("s_waitcnt lgkmcnt(0)" ::: "memory");

            // ---- prefetch row j+1 (stays in flight across the fence) ----
            load_row(j + 1, curm, curh);

            // ---- horizontal 11-tap conv at col x0+lane ----
            v2f hMu = (v2f){0.f, 0.f};
            v2f hSP = (v2f){0.f, 0.f};
            #pragma unroll
            for (int k = 0; k < KW; ++k) {
                const v2f t = wrow[lane + k];            // ds_read_b64
                const v2f gk = (v2f){g[k], g[k]};
                const v2f spv = (v2f){fmaf(t.x, t.x, t.y * t.y), t.x * t.y};
                hMu = __builtin_elementwise_fma(gk, t,   hMu);
                hSP = __builtin_elementwise_fma(gk, spv, hSP);
            }

            // ---- vertical scatter; slot s==P gets its FIRST tap: assign ----
            #pragma unroll
            for (int s = 0; s < KW; ++s) {
                const float wt = g[(P - s + KW) % KW];
                const v2f wv2 = (v2f){wt, wt};
                if (s == P) {
                    aMu[s] = wv2 * hMu;
                    aSP[s] = wv2 * hSP;
                } else {
                    aMu[s] = __builtin_elementwise_fma(wv2, hMu, aMu[s]);
                    aSP[s] = __builtin_elementwise_fma(wv2, hSP, aSP[s]);
                }
            }

            // ---- emit output row oy = y0 + j - 10 from slot (P+1)%11 ----
            const int oy = y0 + j - 2 * RAD;
            if (j >= 2 * RAD && oy < IMG_H) {   // wave-uniform
                const int e2 = (P + 1) % KW;
                const v2f mu = aMu[e2];
                const v2f SP = aSP[e2];
                const v2f musq = mu * mu;
                const float mu12  = mu.x * mu.y;
                const float musum = musq.x + musq.y;
                const float ssum  = SP.x - musum;        // sigma1^2+sigma2^2
                const float s12   = SP.y - mu12;         // sigma12
                const float num = fmaf(2.f, mu12, C1F) * fmaf(2.f, s12, C2F);
                const float den = (musum + C1F) * (ssum + C2F);
                acc = fmaf(num, __builtin_amdgcn_rcpf(den), acc);
            }
        }
    }

    // ---- block reduction, one atomic per block ----
    #pragma unroll
    for (int off = 32; off > 0; off >>= 1)
        acc += __shfl_xor(acc, off, 64);
    if (lane == 0) red[wvi] = acc;
    __syncthreads();
    if (tid == 0) {
        const float s = red[0] + red[1] + red[2] + red[3];
        atomicAdd(out, s * inv_n);
    }
}

extern "C" void kernel_launch(void* const* d_in, const int* in_sizes, int n_in,
                              void* d_out, int out_size, void* d_ws, size_t ws_size,
                              hipStream_t stream) {
    (void)in_sizes; (void)n_in; (void)d_ws; (void)ws_size;
    const float* img1 = (const float*)d_in[0];
    const float* img2 = (const float*)d_in[1];
    float* out = (float*)d_out;

    // d_out is re-poisoned to 0xAA before every launch; zero it (capture-safe).
    hipMemsetAsync(out, 0, (size_t)out_size * sizeof(float), stream);

    const float inv_n = 1.0f / (16.0f * 3.0f * 512.0f * 512.0f);
    // x: 2 blocks x 4 waves = 8 col-strips of 64; y: 16 tiles of 34 rows
    // (tail masked); z: 48 planes.  1536 blocks, 6144 waves.
    dim3 grid(2, 16, 48);
    ssim_fused_kernel<<<grid, dim3(256, 1, 1), 0, stream>>>(img1, img2, out, inv_n);
}

// Round 9
// 154.018 us; speedup vs baseline: 1.2041x; 1.2041x over previous
//
#include <hip/hip_runtime.h>
#include <math.h>

// SSIM fused single pass, v9 = v5 (best measured, 67 us) + forced packed fp32.
// R5-R8 post-mortem: R5's measured 318 VALU inst/iter matches a model where
// __builtin_elementwise_fma on float2 is NOT fused to v_pk_fma_f32 (every
// packed op = 2 scalar v_fma_f32). MI355X's 157 TF fp32 is only reachable via
// VOP3P packed fp32 (scalar ceiling 78.6 TF). v9 forces v_pk_fma_f32 /
// v_pk_mul_f32 via inline asm (tied accumulator, non-volatile so the
// scheduler stays free) for the h-conv and v-scatter (176 scalar FMAs/iter ->
// 88 packed). Gaussian symmetry g[k]==g[10-k] -> 6 packed weight regs.
// Everything else is v5 verbatim: 2 cols/thread, 4 vertical quantities
// (mu1,mu2,S=E[x^2]+E[y^2],P=E[xy]), v4f LDS rows (ds_read_b128),
// wave-private double-buffered staging + one __threadfence_block per iter,
// register prefetch of row j+1, rcp division (~1e-7 err), TY=34, grid 768.

#define KW 11
#define RAD 5
#define IMG_W 512
#define IMG_H 512
#define TY 34                // output rows per wave tile; 44 iters = 4*11 phases
#define NJB 4
#define NV4 70               // 140 staged (a,b) pairs = 70 v4f per row buffer
#define C1F 0.0001f          // 0.01^2
#define C2F 0.0009f          // 0.03^2

typedef float v2f __attribute__((ext_vector_type(2)));
typedef float v4f __attribute__((ext_vector_type(4)));

// acc += a*b, packed fp32 (VOP3P, 64-bit VGPR-pair operands).
static __device__ __forceinline__ void pk_fma(v2f& acc, v2f a, v2f b) {
    asm("v_pk_fma_f32 %0, %1, %2, %0" : "+v"(acc) : "v"(a), "v"(b));
}
// d = a*b, packed fp32.
static __device__ __forceinline__ v2f pk_mul(v2f a, v2f b) {
    v2f d;
    asm("v_pk_mul_f32 %0, %1, %2" : "=v"(d) : "v"(a), "v"(b));
    return d;
}

// weight index -> symmetric storage index (g[w] == g[10-w])
#define GI(w) ((w) < 6 ? (w) : 10 - (w))

__global__ __launch_bounds__(256) void ssim_fused_kernel(
    const float* __restrict__ img1,
    const float* __restrict__ img2,
    float* __restrict__ out,
    float inv_n)
{
    __shared__ v4f rows[4][2][NV4];   // [wave][double-buffer][v4f = 2 pairs]
    __shared__ float red[4];

    const int tid  = threadIdx.x;
    const int lane = tid & 63;
    const int wvi  = tid >> 6;

    const int x0 = wvi * 128;              // wave's 128-col strip
    const int y0 = blockIdx.x * TY;        // wave's first output row

    const size_t pbase = (size_t)blockIdx.y * (size_t)(IMG_W * IMG_H);
    const float* __restrict__ p1 = img1 + pbase;
    const float* __restrict__ p2 = img2 + pbase;

    // Gaussian weights in double (matches float64 np reference). Symmetric:
    // only 6 distinct values, stored packed {g,g} for VOP3P operands.
    v2f g2[6];
    {
        double t[KW];
        double s = 0.0;
        #pragma unroll
        for (int i = 0; i < KW; ++i) {
            const double c = (double)(i - RAD);
            t[i] = exp(-(c * c) / 4.5);   // 2*sigma^2 = 4.5
            s += t[i];
        }
        #pragma unroll
        for (int i = 0; i < 6; ++i) {
            const float gi = (float)(t[i] / s);
            g2[i] = (v2f){gi, gi};
        }
    }

    // Staged entries cover cols x0-6 .. x0+133 (140 entries, even base for
    // aligned float2 loads). Lane t owns entries {2t,2t+1}; lanes 0..5 also
    // stage halo entries {128+2t, 129+2t}.
    const int cm  = x0 - 6 + 2 * lane;                 // main col (even)
    const int cmc = min(max(cm, 0), IMG_W - 2);        // clamped, stays even
    const float mm0 = (cm     >= 0 && cm     < IMG_W) ? 1.f : 0.f;
    const float mm1 = (cm + 1 >= 0 && cm + 1 < IMG_W) ? 1.f : 0.f;
    const int ch  = x0 + 122 + 2 * lane;               // halo col (lanes 0..5)
    const int chc = min(max(ch, 0), IMG_W - 2);
    const float mh0 = (ch     < IMG_W) ? 1.f : 0.f;
    const float mh1 = (ch + 1 < IMG_W) ? 1.f : 0.f;

    // Load row (y0-RAD+j) into interleaved+masked (a0,b0,a1,b1) v4f regs.
    auto load_row = [&](int j, v4f& vm, v4f& vh) {
        const int ir = y0 - RAD + j;
        vm = (v4f){0.f, 0.f, 0.f, 0.f};
        vh = (v4f){0.f, 0.f, 0.f, 0.f};
        if ((unsigned)ir < (unsigned)IMG_H) {   // wave-uniform branch
            const float* r1 = p1 + ir * IMG_W;
            const float* r2 = p2 + ir * IMG_W;
            const v2f a = *reinterpret_cast<const v2f*>(r1 + cmc);
            const v2f b = *reinterpret_cast<const v2f*>(r2 + cmc);
            vm = (v4f){a.x * mm0, b.x * mm0, a.y * mm1, b.y * mm1};
            if (lane < 6) {
                const v2f ah = *reinterpret_cast<const v2f*>(r1 + chc);
                const v2f bh = *reinterpret_cast<const v2f*>(r2 + chc);
                vh = (v4f){ah.x * mh0, bh.x * mh0, ah.y * mh1, bh.y * mh1};
            }
        }
    };

    // V scatter accumulators for the thread's 2 columns (A=x0+2l, B=x0+2l+1):
    // slot s holds output row m with m%11==s.  (mu1,mu2) and (S,P) per px.
    v2f aMuA[KW], aSPA[KW], aMuB[KW], aSPB[KW];
    #pragma unroll
    for (int s = 0; s < KW; ++s) {
        aMuA[s] = (v2f){0.f, 0.f}; aSPA[s] = (v2f){0.f, 0.f};
        aMuB[s] = (v2f){0.f, 0.f}; aSPB[s] = (v2f){0.f, 0.f};
    }

    v4f curm, curh;
    load_row(0, curm, curh);

    float acc = 0.f;

    #pragma clang loop unroll(disable)
    for (int jb = 0; jb < NJB; ++jb) {
        #pragma unroll
        for (int P = 0; P < KW; ++P) {
            const int j   = jb * KW + P;        // 0..43
            const int buf = j & 1;
            v4f* __restrict__ wrow = rows[wvi][buf];

            // ---- stage row j (regs -> wave-private LDS) ----
            wrow[lane] = curm;                          // ds_write_b128
            if (lane < 6) wrow[64 + lane] = curh;
            __threadfence_block();   // orders W_j < R_j (and R_j < W_{j+2})

            // ---- prefetch row j+1 (latency covered by this iter's math) ----
            load_row(j + 1, curm, curh);

            // ---- read the window: v4f slots lane..lane+6 (pairs 2l..2l+13) --
            v4f e[7];
            #pragma unroll
            for (int r = 0; r < 7; ++r) e[r] = wrow[lane + r];   // ds_read_b128

            // ---- incremental pair walk: pairs i=1..12 (rel 2l) ----
            // col A (x0+2l)   uses pairs 1..11 with weight g[i-1]
            // col B (x0+2l+1) uses pairs 2..12 with weight g[i-2]
            v2f hMuA, hSPA, hMuB, hSPB;
            #pragma unroll
            for (int i = 1; i <= 12; ++i) {
                const v4f q = e[i >> 1];
                const v2f t = (i & 1) ? (v2f){q.z, q.w} : (v2f){q.x, q.y};
                const v2f spv = (v2f){fmaf(t.x, t.x, t.y * t.y), t.x * t.y};
                if (i <= 11) {
                    const v2f gA = g2[GI(i - 1)];
                    if (i == 1) { hMuA = pk_mul(gA, t); hSPA = pk_mul(gA, spv); }
                    else        { pk_fma(hMuA, gA, t);  pk_fma(hSPA, gA, spv); }
                }
                if (i >= 2) {
                    const v2f gB = g2[GI(i - 2)];
                    if (i == 2) { hMuB = pk_mul(gB, t); hSPB = pk_mul(gB, spv); }
                    else        { pk_fma(hMuB, gB, t);  pk_fma(hSPB, gB, spv); }
                }
            }

            // ---- vertical scatter; slot s==P gets its FIRST tap: assign ----
            #pragma unroll
            for (int s = 0; s < KW; ++s) {
                const v2f w2 = g2[GI((P - s + KW) % KW)];
                if (s == P) {
                    aMuA[s] = pk_mul(w2, hMuA);  aSPA[s] = pk_mul(w2, hSPA);
                    aMuB[s] = pk_mul(w2, hMuB);  aSPB[s] = pk_mul(w2, hSPB);
                } else {
                    pk_fma(aMuA[s], w2, hMuA);   pk_fma(aSPA[s], w2, hSPA);
                    pk_fma(aMuB[s], w2, hMuB);   pk_fma(aSPB[s], w2, hSPB);
                }
            }

            // ---- emit output row oy = y0 + j - 10 from slot (P+1)%11 ----
            const int oy = y0 + j - 2 * RAD;
            if (j >= 2 * RAD && oy < IMG_H) {   // wave-uniform
                const int e2 = (P + 1) % KW;
                #pragma unroll
                for (int px = 0; px < 2; ++px) {
                    const v2f mu = px ? aMuB[e2] : aMuA[e2];
                    const v2f SP = px ? aSPB[e2] : aSPA[e2];
                    const v2f musq = mu * mu;
                    const float mu12  = mu.x * mu.y;
                    const float musum = musq.x + musq.y;
                    const float ssum  = SP.x - musum;        // sigma1^2+sigma2^2
                    const float s12   = SP.y - mu12;         // sigma12
                    const float num = fmaf(2.f, mu12, C1F) * fmaf(2.f, s12, C2F);
                    const float den = (musum + C1F) * (ssum + C2F);
                    acc = fmaf(num, __builtin_amdgcn_rcpf(den), acc);
                }
            }
        }
    }

    // ---- block reduction, one atomic per block ----
    #pragma unroll
    for (int off = 32; off > 0; off >>= 1)
        acc += __shfl_xor(acc, off, 64);
    if (lane == 0) red[wvi] = acc;
    __syncthreads();
    if (tid == 0) {
        const float s = red[0] + red[1] + red[2] + red[3];
        atomicAdd(out, s * inv_n);
    }
}

extern "C" void kernel_launch(void* const* d_in, const int* in_sizes, int n_in,
                              void* d_out, int out_size, void* d_ws, size_t ws_size,
                              hipStream_t stream) {
    (void)in_sizes; (void)n_in; (void)d_ws; (void)ws_size;
    const float* img1 = (const float*)d_in[0];
    const float* img2 = (const float*)d_in[1];
    float* out = (float*)d_out;

    // d_out is re-poisoned to 0xAA before every launch; zero it (capture-safe).
    hipMemsetAsync(out, 0, (size_t)out_size * sizeof(float), stream);

    const float inv_n = 1.0f / (16.0f * 3.0f * 512.0f * 512.0f);
    // 16 y-tiles (34 rows, tail masked) x 48 planes; 4 waves = 4 col-strips.
    dim3 grid(16, 48, 1);   // 768 blocks = exactly 3 blocks/CU
    ssim_fused_kernel<<<grid, dim3(256, 1, 1), 0, stream>>>(img1, img2, out, inv_n);
}